// Round 3
// baseline (876.731 us; speedup 1.0000x reference)
//
#include <hip/hip_runtime.h>
#include <hip/hip_bf16.h>
#include <math.h>

// out[n,:] = s1 .* FWHT( (u/4096) .* FWHT( s2 .* x[n,:] ) ),
// u = g_mu + softplus(g_rho)*epsilon, FWHT unnormalized Walsh-Hadamard.
// Radix-64 (D = 64*64), one wave per row, 64 floats/lane, two LDS 64x64
// transposes (XOR-swizzled, measured conflict-free).
// NEW: 128-thread blocks = 2 waves / 2 rows SHARING one 16 KB buffer in
// alternating barrier slots -> 20 waves/CU instead of 10.

#define WHVI_D 4096

__device__ __forceinline__ void fwht64(float v[64]) {
#pragma unroll
    for (int s = 1; s < 64; s <<= 1) {
#pragma unroll
        for (int i = 0; i < 64; ++i) {
            if ((i & s) == 0) {
                float a = v[i];
                float b = v[i | s];
                v[i] = a + b;
                v[i | s] = a - b;
            }
        }
    }
}

__global__ __launch_bounds__(256)
void u_precompute_kernel(const float* __restrict__ g_mu,
                         const float* __restrict__ g_rho,
                         const float* __restrict__ g_eps,
                         float* __restrict__ u) {
    int i = blockIdx.x * 256 + threadIdx.x;  // grid covers exactly 4096
    float rho = g_rho[i];
    float sp = fmaxf(rho, 0.0f) + __logf(1.0f + __expf(-fabsf(rho)));
    u[i] = (g_mu[i] + sp * g_eps[i]) * (1.0f / 4096.0f);
}

// Swizzled LDS word address for logical element (h, l):
//   A(h,l) = h*64 + (((l>>2) ^ (h&15)) << 2) + (l&3)
// b128 row phase: float4-bank-group (c ^ (h&7)) spreads all 8 groups.
// b32 column phase: bijective onto 64 consecutive words -> 2 lanes/bank, free.

__device__ __forceinline__ void lgkm_fence() {
    asm volatile("s_waitcnt lgkmcnt(0)" ::: "memory");
    __builtin_amdgcn_sched_barrier(0);
}

// T1: write per-lane rows (b128), read columns (b32). regs d0 -> d1.
__device__ __forceinline__ void transpose_rows_to_cols(float* lds, float v[64], int l) {
#pragma unroll
    for (int c = 0; c < 16; ++c) {
        int a4 = l * 16 + (c ^ (l & 15));
        *reinterpret_cast<float4*>(&lds[a4 << 2]) =
            make_float4(v[4 * c + 0], v[4 * c + 1], v[4 * c + 2], v[4 * c + 3]);
    }
    lgkm_fence();
#pragma unroll
    for (int r = 0; r < 64; ++r) {
        int addr = r * 64 + ((((l >> 2) ^ (r & 15)) << 2) | (l & 3));
        v[r] = lds[addr];
    }
}

// T2: write columns (b32), read per-lane rows (b128). regs e1 -> e0.
__device__ __forceinline__ void transpose_cols_to_rows(float* lds, float v[64], int l) {
#pragma unroll
    for (int r = 0; r < 64; ++r) {
        int addr = r * 64 + ((((l >> 2) ^ (r & 15)) << 2) | (l & 3));
        lds[addr] = v[r];
    }
    lgkm_fence();
#pragma unroll
    for (int c = 0; c < 16; ++c) {
        int a4 = l * 16 + (c ^ (l & 15));
        float4 t = *reinterpret_cast<const float4*>(&lds[a4 << 2]);
        v[4 * c + 0] = t.x;
        v[4 * c + 1] = t.y;
        v[4 * c + 2] = t.z;
        v[4 * c + 3] = t.w;
    }
}

// middle: FWHT#1 high digit, diagonal u, FWHT#2 first (in-reg) digit.
__device__ __forceinline__ void middle_phase(float v[64], int l,
                                             const float* __restrict__ u) {
    fwht64(v);  // regs hold d1 -> y[r*64 + l]
#pragma unroll
    for (int r = 0; r < 64; ++r) v[r] *= u[r * 64 + l];  // lane-coalesced
    fwht64(v);  // FWHT#2 on the digit already in regs
}

template <int WAVES>  // 2 = paired kernel, 1 = single-row fallback
__global__ __launch_bounds__(64 * WAVES, WAVES == 2 ? 5 : 0)
void whvi64_kernel(const float* __restrict__ x,
                   const float* __restrict__ s1,
                   const float* __restrict__ s2,
                   const float* __restrict__ u,
                   float* __restrict__ out,
                   int nrows, int row0) {
    __shared__ float lds[WHVI_D];

    const int l = threadIdx.x & 63;
    const int w = threadIdx.x >> 6;  // 0 or 1
    const int row = row0 + blockIdx.x * WAVES + w;
    if (row >= nrows) return;  // only possible in the WAVES==1 tail

    float v[64];

    // ---- load x[row, l*64 + 0..63], scale by s2 (16x b128 per lane) ----
    {
        const float4* xv = reinterpret_cast<const float4*>(x + (size_t)row * WHVI_D + l * 64);
        const float4* sv = reinterpret_cast<const float4*>(s2 + l * 64);
#pragma unroll
        for (int c = 0; c < 16; ++c) {
            float4 a = xv[c];
            float4 s = sv[c];
            v[4 * c + 0] = a.x * s.x;
            v[4 * c + 1] = a.y * s.y;
            v[4 * c + 2] = a.z * s.z;
            v[4 * c + 3] = a.w * s.w;
        }
    }

    // ---- pass 1: low digit in regs ----
    fwht64(v);

    if (WAVES == 1) {
        transpose_rows_to_cols(lds, v, l);
        middle_phase(v, l, u);
        transpose_cols_to_rows(lds, v, l);
    } else {
        // Slot schedule (buffer owner per slot): A, B, A, B.
        // A: T1 | bar | middle | bar | T2  | bar | tail
        // B: -- | bar | T1     | bar | mid | bar | T2, tail
        if (w == 0) transpose_rows_to_cols(lds, v, l);
        __syncthreads();
        if (w == 1) transpose_rows_to_cols(lds, v, l);
        else        middle_phase(v, l, u);
        __syncthreads();
        if (w == 0) transpose_cols_to_rows(lds, v, l);
        else        middle_phase(v, l, u);
        __syncthreads();
        if (w == 1) transpose_cols_to_rows(lds, v, l);
    }

    // ---- final pass: last digit in regs -> natural order ----
    fwht64(v);

    // ---- s1 scale + store (b128) ----
    {
        const float4* sv = reinterpret_cast<const float4*>(s1 + l * 64);
        float4* ov = reinterpret_cast<float4*>(out + (size_t)row * WHVI_D + l * 64);
#pragma unroll
        for (int c = 0; c < 16; ++c) {
            float4 s = sv[c];
            ov[c] = make_float4(v[4 * c + 0] * s.x, v[4 * c + 1] * s.y,
                                v[4 * c + 2] * s.z, v[4 * c + 3] * s.w);
        }
    }
}

extern "C" void kernel_launch(void* const* d_in, const int* in_sizes, int n_in,
                              void* d_out, int out_size, void* d_ws, size_t ws_size,
                              hipStream_t stream) {
    const float* x     = (const float*)d_in[0];
    const float* s1    = (const float*)d_in[1];
    const float* s2    = (const float*)d_in[2];
    const float* g_mu  = (const float*)d_in[3];
    const float* g_rho = (const float*)d_in[4];
    const float* g_eps = (const float*)d_in[5];
    // d_in[6] is H — unused; the FWHT realizes it exactly.
    float* out = (float*)d_out;

    const int nrows = in_sizes[0] / WHVI_D;  // 8192

    float* u = (float*)d_ws;  // ws_size is comfortably >= 16 KB
    u_precompute_kernel<<<WHVI_D / 256, 256, 0, stream>>>(g_mu, g_rho, g_eps, u);

    const int npairs = nrows / 2;
    if (npairs > 0)
        whvi64_kernel<2><<<npairs, 128, 0, stream>>>(x, s1, s2, u, out, nrows, 0);
    if (nrows & 1)
        whvi64_kernel<1><<<1, 64, 0, stream>>>(x, s1, s2, u, out, nrows, npairs * 2);
}

// Round 4
// 95.726 us; speedup vs baseline: 9.1588x; 9.1588x over previous
//
#include <hip/hip_runtime.h>
#include <hip/hip_bf16.h>
#include <math.h>

// out[n,:] = s1 .* FWHT( (u/4096) .* FWHT( s2 .* x[n,:] ) ),
// u = g_mu + softplus(g_rho)*epsilon, FWHT unnormalized Walsh-Hadamard.
// Radix-64 (D = 64*64), one wave per row, 64 floats/lane held as 32x float2
// (packed v_pk_add_f32 butterflies), two XOR-swizzled LDS 64x64 transposes
// (measured conflict-free). 2 waves/block share one 16 KB buffer in
// alternating barrier slots. NO min-occupancy launch bound (round 3: the
// bound capped VGPR at 48 -> v[64] spilled -> 15x HBM traffic, 877 us).

#define WHVI_D 4096

typedef float f2 __attribute__((ext_vector_type(2)));

__device__ __forceinline__ void fwht64(f2 w[32]) {
    // stride-1 (intra-register) level: scalar add/sub
#pragma unroll
    for (int k = 0; k < 32; ++k) {
        float a = w[k].x, b = w[k].y;
        w[k].x = a + b;
        w[k].y = a - b;
    }
    // strides 2..64 elements (1..32 regs): float2 ops -> v_pk_add_f32
#pragma unroll
    for (int s = 1; s < 32; s <<= 1) {
#pragma unroll
        for (int i = 0; i < 32; ++i) {
            if ((i & s) == 0) {
                f2 a = w[i], b = w[i | s];
                w[i] = a + b;
                w[i | s] = a - b;
            }
        }
    }
}

__global__ __launch_bounds__(256)
void u_precompute_kernel(const float* __restrict__ g_mu,
                         const float* __restrict__ g_rho,
                         const float* __restrict__ g_eps,
                         float* __restrict__ u) {
    int i = blockIdx.x * 256 + threadIdx.x;  // grid covers exactly 4096
    float rho = g_rho[i];
    float sp = fmaxf(rho, 0.0f) + __logf(1.0f + __expf(-fabsf(rho)));
    u[i] = (g_mu[i] + sp * g_eps[i]) * (1.0f / 4096.0f);
}

// Swizzled LDS word address for logical element (h, l):
//   A(h,l) = h*64 + (((l>>2) ^ (h&15)) << 2) + (l&3)
// b128 row phase: float4-bank-group (c ^ (h&7)) spreads all 8 groups.
// b32 column phase: bijective onto 64 consecutive words -> 2 lanes/bank, free.
// (Round 2/3 measured SQ_LDS_BANK_CONFLICT == 0 with this map.)

__device__ __forceinline__ void lgkm_fence() {
    asm volatile("s_waitcnt lgkmcnt(0)" ::: "memory");
    __builtin_amdgcn_sched_barrier(0);
}

// T1: write per-lane rows (b128), read columns (b32). regs d0 -> d1.
__device__ __forceinline__ void transpose_rows_to_cols(float* lds, f2 w[32], int l) {
#pragma unroll
    for (int c = 0; c < 16; ++c) {
        int a4 = l * 16 + (c ^ (l & 15));
        *reinterpret_cast<float4*>(&lds[a4 << 2]) =
            make_float4(w[2 * c].x, w[2 * c].y, w[2 * c + 1].x, w[2 * c + 1].y);
    }
    lgkm_fence();
#pragma unroll
    for (int r = 0; r < 64; ++r) {
        int addr = r * 64 + ((((l >> 2) ^ (r & 15)) << 2) | (l & 3));
        w[r >> 1][r & 1] = lds[addr];   // compile-time lane of the f2
    }
}

// T2: write columns (b32), read per-lane rows (b128). regs e1 -> e0.
__device__ __forceinline__ void transpose_cols_to_rows(float* lds, f2 w[32], int l) {
#pragma unroll
    for (int r = 0; r < 64; ++r) {
        int addr = r * 64 + ((((l >> 2) ^ (r & 15)) << 2) | (l & 3));
        lds[addr] = w[r >> 1][r & 1];
    }
    lgkm_fence();
#pragma unroll
    for (int c = 0; c < 16; ++c) {
        int a4 = l * 16 + (c ^ (l & 15));
        float4 t = *reinterpret_cast<const float4*>(&lds[a4 << 2]);
        w[2 * c] = f2{t.x, t.y};
        w[2 * c + 1] = f2{t.z, t.w};
    }
}

// middle: FWHT#1 high digit, diagonal u, FWHT#2 first (in-reg) digit.
__device__ __forceinline__ void middle_phase(f2 w[32], int l,
                                             const float* __restrict__ u) {
    fwht64(w);  // regs hold high digit -> y[r*64 + l]
#pragma unroll
    for (int k = 0; k < 32; ++k) {
        f2 um = f2{u[(2 * k) * 64 + l], u[(2 * k + 1) * 64 + l]};  // lane-coalesced
        w[k] *= um;                                                // v_pk_mul_f32
    }
    fwht64(w);  // FWHT#2 on the digit already in regs
}

template <int WAVES>  // 2 = paired kernel, 1 = single-row fallback
__global__ __launch_bounds__(64 * WAVES)
void whvi64_kernel(const float* __restrict__ x,
                   const float* __restrict__ s1,
                   const float* __restrict__ s2,
                   const float* __restrict__ u,
                   float* __restrict__ out,
                   int nrows, int row0) {
    __shared__ float lds[WHVI_D];

    const int l = threadIdx.x & 63;
    const int w_id = threadIdx.x >> 6;  // 0 or 1
    const int row = row0 + blockIdx.x * WAVES + w_id;
    if (row >= nrows) return;  // only possible in the WAVES==1 tail

    f2 w[32];

    // ---- load x[row, l*64 + 0..63], scale by s2 (16x b128 per lane) ----
    {
        const float4* xv = reinterpret_cast<const float4*>(x + (size_t)row * WHVI_D + l * 64);
        const float4* sv = reinterpret_cast<const float4*>(s2 + l * 64);
#pragma unroll
        for (int c = 0; c < 16; ++c) {
            float4 a = xv[c];
            float4 s = sv[c];
            w[2 * c] = f2{a.x * s.x, a.y * s.y};
            w[2 * c + 1] = f2{a.z * s.z, a.w * s.w};
        }
    }

    // ---- pass 1: low digit in regs ----
    fwht64(w);

    if (WAVES == 1) {
        transpose_rows_to_cols(lds, w, l);
        middle_phase(w, l, u);
        transpose_cols_to_rows(lds, w, l);
    } else {
        // Buffer owner per slot: A, B, A, B.
        // A: T1 | bar | middle | bar | T2  | bar | store
        // B: -- | bar | T1     | bar | mid | bar | T2, store
        if (w_id == 0) transpose_rows_to_cols(lds, w, l);
        __syncthreads();
        if (w_id == 1) transpose_rows_to_cols(lds, w, l);
        else           middle_phase(w, l, u);
        __syncthreads();
        if (w_id == 0) transpose_cols_to_rows(lds, w, l);
        else           middle_phase(w, l, u);
        __syncthreads();
        if (w_id == 1) transpose_cols_to_rows(lds, w, l);
    }

    // ---- final pass: last digit in regs -> natural order ----
    fwht64(w);

    // ---- s1 scale + store (b128) ----
    {
        const float4* sv = reinterpret_cast<const float4*>(s1 + l * 64);
        float4* ov = reinterpret_cast<float4*>(out + (size_t)row * WHVI_D + l * 64);
#pragma unroll
        for (int c = 0; c < 16; ++c) {
            float4 s = sv[c];
            ov[c] = make_float4(w[2 * c].x * s.x, w[2 * c].y * s.y,
                                w[2 * c + 1].x * s.z, w[2 * c + 1].y * s.w);
        }
    }
}

extern "C" void kernel_launch(void* const* d_in, const int* in_sizes, int n_in,
                              void* d_out, int out_size, void* d_ws, size_t ws_size,
                              hipStream_t stream) {
    const float* x     = (const float*)d_in[0];
    const float* s1    = (const float*)d_in[1];
    const float* s2    = (const float*)d_in[2];
    const float* g_mu  = (const float*)d_in[3];
    const float* g_rho = (const float*)d_in[4];
    const float* g_eps = (const float*)d_in[5];
    // d_in[6] is H — unused; the FWHT realizes it exactly.
    float* out = (float*)d_out;

    const int nrows = in_sizes[0] / WHVI_D;  // 8192

    float* u = (float*)d_ws;  // ws_size >= 16 KB (verified: rounds 2-3 used it)
    u_precompute_kernel<<<WHVI_D / 256, 256, 0, stream>>>(g_mu, g_rho, g_eps, u);

    const int npairs = nrows / 2;
    if (npairs > 0)
        whvi64_kernel<2><<<npairs, 128, 0, stream>>>(x, s1, s2, u, out, nrows, 0);
    if (nrows & 1)
        whvi64_kernel<1><<<1, 64, 0, stream>>>(x, s1, s2, u, out, nrows, npairs * 2);
}

// Round 5
// 66.431 us; speedup vs baseline: 13.1977x; 1.4410x over previous
//
#include <hip/hip_runtime.h>
#include <hip/hip_bf16.h>
#include <math.h>

// out[n,:] = s1 .* FWHT( (u/4096) .* FWHT( s2 .* x[n,:] ) ),
// u = g_mu + softplus(g_rho)*epsilon, FWHT = unnormalized Walsh-Hadamard.
//
// Structure (R5): radix-16 (D = 16^3), 256 threads per block, ONE ROW PAIR
// per block packed into float2 lanes (.x = row 2b, .y = row 2b+1):
//  - 6 in-register fwht16 passes, all v_pk_add_f32
//  - 4 LDS digit rotations on f2 elements (b64/b128 ops), XOR-swizzled,
//    uniform bank spread; rotations 1/4 are intra-wave (lgkm fence only),
//    rotations 2/3 need the only two __syncthreads()
//  - u precomputed once (removes per-thread softplus transcendentals)
// R1 (single-row b32 version) = 72 us, DS-pipe-bound; this halves DS+VALU
// per row at comparable occupancy (32 KB LDS -> 5 blocks -> 20 waves/CU).

#define WHVI_D 4096

typedef float f2 __attribute__((ext_vector_type(2)));

__device__ __forceinline__ void fwht16(f2 v[16]) {
#pragma unroll
    for (int s = 1; s < 16; s <<= 1) {
#pragma unroll
        for (int i = 0; i < 16; ++i) {
            if ((i & s) == 0) {
                f2 a = v[i], b = v[i | s];
                v[i] = a + b;       // v_pk_add_f32
                v[i | s] = a - b;   // v_pk_add_f32 (neg)
            }
        }
    }
}

__global__ __launch_bounds__(256)
void u_precompute_kernel(const float* __restrict__ g_mu,
                         const float* __restrict__ g_rho,
                         const float* __restrict__ g_eps,
                         float* __restrict__ u) {
    int i = blockIdx.x * 256 + threadIdx.x;  // grid covers exactly 4096
    float rho = g_rho[i];
    float sp = fmaxf(rho, 0.0f) + __logf(1.0f + __expf(-fabsf(rho)));
    u[i] = (g_mu[i] + sp * g_eps[i]) * (1.0f / 4096.0f);
}

__device__ __forceinline__ void lgkm_fence() {
    asm volatile("s_waitcnt lgkmcnt(0)" ::: "memory");
    __builtin_amdgcn_sched_barrier(0);
}

// LDS layout in f2 units: A(c2,c1,c0) = c2*256 + c1*16 + (c0 ^ (c1 & 14)).
// XOR keeps c0-pairs contiguous (b128-able) and spreads banks:
//  - b128 row ops: 8 words/bank uniform (minimum service time)
//  - b64 strided ops: 4 lanes/bank-pair uniform (minimum service time)

__global__ __launch_bounds__(256)
void whvi_pair_kernel(const float* __restrict__ x,
                      const float* __restrict__ s1,
                      const float* __restrict__ s2,
                      const float* __restrict__ u,
                      float* __restrict__ out,
                      int nrows) {
    __shared__ __align__(16) f2 lds[WHVI_D];  // 32 KB

    const int t = threadIdx.x;   // 0..255
    const int P = t >> 4;        // 0..15  (16-thread group: intra-wave)
    const int Q = t & 15;        // 0..15
    const int r0 = blockIdx.x * 2;
    const int r1_valid = (r0 + 1 < nrows);
    const size_t base0 = (size_t)r0 * WHVI_D;
    const size_t base1 = (size_t)(r0 + (r1_valid ? 1 : 0)) * WHVI_D;

    f2 v[16];

    // ---- load the row pair, scale by s2 (b128, coalesced) ----
    {
        const float4* x0v = reinterpret_cast<const float4*>(x + base0 + t * 16);
        const float4* x1v = reinterpret_cast<const float4*>(x + base1 + t * 16);
        const float4* sv  = reinterpret_cast<const float4*>(s2 + t * 16);
#pragma unroll
        for (int c = 0; c < 4; ++c) {
            float4 a = x0v[c], b = x1v[c], s = sv[c];
            v[4 * c + 0] = f2{a.x * s.x, b.x * s.x};
            v[4 * c + 1] = f2{a.y * s.y, b.y * s.y};
            v[4 * c + 2] = f2{a.z * s.z, b.z * s.z};
            v[4 * c + 3] = f2{a.w * s.w, b.w * s.w};
        }
    }

    // ---- pass 1: digit d0 (regs) ----
    fwht16(v);

    // ---- rot1: write (P,Q,j) as b128, read (P,j,Q) as b64. Intra-wave. ----
#pragma unroll
    for (int c = 0; c < 8; ++c) {
        int a4 = P * 256 + Q * 16 + ((2 * c) ^ (Q & 14));  // even -> 16B aligned
        *reinterpret_cast<float4*>(&lds[a4]) =
            make_float4(v[2 * c].x, v[2 * c].y, v[2 * c + 1].x, v[2 * c + 1].y);
    }
    lgkm_fence();
#pragma unroll
    for (int j = 0; j < 16; ++j)
        v[j] = lds[P * 256 + j * 16 + (Q ^ (j & 14))];

    // ---- pass 2: digit d1 ----
    fwht16(v);

    // ---- rot2: write back to the addrs this thread just read (WAR-safe,
    //      DS pipe is FIFO per wave), barrier, read (j,P,Q) ----
#pragma unroll
    for (int j = 0; j < 16; ++j)
        lds[P * 256 + j * 16 + (Q ^ (j & 14))] = v[j];
    __syncthreads();
#pragma unroll
    for (int j = 0; j < 16; ++j)
        v[j] = lds[j * 256 + P * 16 + (Q ^ (P & 14))];

    // ---- pass 3: digit d2 -> FWHT#1 done; v[j] = y[j*256 + t] ----
    fwht16(v);

    // ---- diagonal u (1/4096 folded in); u[j*256+t] lane-coalesced, L2-hot ----
#pragma unroll
    for (int j = 0; j < 16; ++j) {
        float uu = u[j * 256 + t];
        v[j] *= uu;   // v_pk_mul_f32, scalar splat
    }

    // ---- pass 4: digit e2 (already in regs) ----
    fwht16(v);

    // ---- rot3: write back same addrs as rot2-read, barrier, read (P,j,Q) ----
#pragma unroll
    for (int j = 0; j < 16; ++j)
        lds[j * 256 + P * 16 + (Q ^ (P & 14))] = v[j];
    __syncthreads();
#pragma unroll
    for (int j = 0; j < 16; ++j)
        v[j] = lds[P * 256 + j * 16 + (Q ^ (j & 14))];

    // ---- pass 5: digit e1 ----
    fwht16(v);

    // ---- rot4: write back same addrs, read (P,Q,j) as b128. Intra-wave. ----
#pragma unroll
    for (int j = 0; j < 16; ++j)
        lds[P * 256 + j * 16 + (Q ^ (j & 14))] = v[j];
    lgkm_fence();
#pragma unroll
    for (int c = 0; c < 8; ++c) {
        int a4 = P * 256 + Q * 16 + ((2 * c) ^ (Q & 14));
        float4 tt = *reinterpret_cast<const float4*>(&lds[a4]);
        v[2 * c]     = f2{tt.x, tt.y};
        v[2 * c + 1] = f2{tt.z, tt.w};
    }

    // ---- pass 6: digit e0 -> natural order, element 16t + j ----
    fwht16(v);

    // ---- s1 scale + store both rows (b128, coalesced) ----
    {
        const float4* s1v = reinterpret_cast<const float4*>(s1 + t * 16);
        float4* o0 = reinterpret_cast<float4*>(out + base0 + t * 16);
        float4* o1 = reinterpret_cast<float4*>(out + base1 + t * 16);
#pragma unroll
        for (int c = 0; c < 4; ++c) {
            float4 s = s1v[c];
            o0[c] = make_float4(v[4 * c + 0].x * s.x, v[4 * c + 1].x * s.y,
                                v[4 * c + 2].x * s.z, v[4 * c + 3].x * s.w);
            if (r1_valid)
                o1[c] = make_float4(v[4 * c + 0].y * s.x, v[4 * c + 1].y * s.y,
                                    v[4 * c + 2].y * s.z, v[4 * c + 3].y * s.w);
        }
    }
}

extern "C" void kernel_launch(void* const* d_in, const int* in_sizes, int n_in,
                              void* d_out, int out_size, void* d_ws, size_t ws_size,
                              hipStream_t stream) {
    const float* x     = (const float*)d_in[0];
    const float* s1    = (const float*)d_in[1];
    const float* s2    = (const float*)d_in[2];
    const float* g_mu  = (const float*)d_in[3];
    const float* g_rho = (const float*)d_in[4];
    const float* g_eps = (const float*)d_in[5];
    // d_in[6] is H — unused; the FWHT realizes it exactly.
    float* out = (float*)d_out;

    const int nrows = in_sizes[0] / WHVI_D;  // 8192

    float* u = (float*)d_ws;  // ws_size >= 16 KB (verified in rounds 2-4)
    u_precompute_kernel<<<WHVI_D / 256, 256, 0, stream>>>(g_mu, g_rho, g_eps, u);

    const int npairs = (nrows + 1) / 2;
    whvi_pair_kernel<<<npairs, 256, 0, stream>>>(x, s1, s2, u, out, nrows);
}